// Round 6
// baseline (233.078 us; speedup 1.0000x reference)
//
#include <hip/hip_runtime.h>

typedef __bf16 bf16;
typedef __bf16 bf16x4 __attribute__((ext_vector_type(4)));
typedef __bf16 bf16x8 __attribute__((ext_vector_type(8)));
typedef float f32x4 __attribute__((ext_vector_type(4)));

#define SEQ 4096
#define EMB 1024

// async global->LDS, 16B per lane; LDS dest = wave-uniform base + lane*16 (m97/m104)
__device__ __forceinline__ void async_copy16(void* lds, const void* g) {
    __builtin_amdgcn_global_load_lds(
        (const __attribute__((address_space(1))) unsigned int*)g,
        (__attribute__((address_space(3))) unsigned int*)lds,
        16, 0, 0);
}

// One prep kernel: fp32->bf16 of x, W_Q|W_K (stacked), W_V; zero rowsum.
__global__ __launch_bounds__(256) void prep_all(const float* __restrict__ x,
                                                const float* __restrict__ wq,
                                                const float* __restrict__ wk,
                                                const float* __restrict__ wv,
                                                bf16* __restrict__ xb,
                                                bf16* __restrict__ wqk,
                                                bf16* __restrict__ wvb,
                                                float* __restrict__ rowsum)
{
    const int u = blockIdx.x * 256 + threadIdx.x;
    const float* src;
    bf16* dst;
    int off;
    if (u < 1048576)      { src = x;  dst = xb;               off = u; }
    else if (u < 1310720) { src = wq; dst = wqk;              off = u - 1048576; }
    else if (u < 1572864) { src = wk; dst = wqk + EMB * EMB;  off = u - 1310720; }
    else if (u < 1835008) { src = wv; dst = wvb;              off = u - 1572864; }
    else {                // u < 1836032: zero rowsum[4096]
        *(float4*)(rowsum + (size_t)(u - 1835008) * 4) = float4{0.f, 0.f, 0.f, 0.f};
        return;
    }
    float4 f = *(const float4*)(src + (size_t)off * 4);
    bf16x4 v = { (bf16)f.x, (bf16)f.y, (bf16)f.z, (bf16)f.w };
    *(bf16x4*)(dst + (size_t)off * 4) = v;
}

// ---------------------------------------------------------------------------
// 256x256 tile GEMM core, BK=32, 512 threads = 8 waves (2 m-waves x 4 n-waves),
// per-wave output 128x64. Derived-waits pipeline, R6 staging-bandwidth rev:
//  - 4 LDS buffers (t&3); staging runs THREE K-tiles ahead (A+B of t+3 issued
//    together post-barrier); counted s_waitcnt vmcnt(4) per tile -> two full
//    tiles of slack for load latency. Buf-reuse race (buf(t+3)==buf(t-1)):
//    closed by lgkmcnt(0) BEFORE the per-tile barrier (all reads of the buffer
//    provably complete before any wave can pass the barrier and overwrite).
//  - 2 phases/tile, reads one phase ahead of their MFMA cluster:
//    PH1(t): issue afB(t); lgkm(4); MFMA mg0 (afA x bgC).
//    PH2(t): lgkm(0); vmcnt(4|0); barrier; stage A+B(t+3); issue afA(t+1)+
//            bgN(t+1); sched_barrier; MFMA mg1 (afB x bgC).
// LDS row stride 32 elems (64B); k-chunk rotation g(r)=(r>>1)&3 on BOTH sides
// (per-lane global-source permutation at staging + read offset): each 16B
// window hit by exactly 2 of 16 lanes -> 2-way = free (verified R5: 0 confl).
// RSUM: per-row sums of A-frags (lane fr = row; q-lanes = disjoint k-chunks).
// ---------------------------------------------------------------------------
template<bool RSUM>
__device__ __forceinline__ void tile_step(int t, int NT,
                                          const bf16* __restrict__ Ab,
                                          const bf16* __restrict__ Bb,
                                          int lda, int ldb,
                                          bf16* __restrict__ As,
                                          bf16* __restrict__ Bs,
                                          bf16* __restrict__ AsD,
                                          bf16* __restrict__ BsD,
                                          int wr, int wc, int fr, int pc,
                                          bf16x8 (&afA)[4], bf16x8 (&afB)[4],
                                          bf16x8 (&bgC)[4], bf16x8 (&bgN)[4],
                                          f32x4 (&acc)[8][4], float (&rsum)[8],
                                          bool rs_active)
{
    // ---------------- PH1: issue afB(t); MFMA mg0(t) = afA x bgC
    {
        const bf16* At = As + (t & 3) * 8192 + (wr * 128 + 64 + fr) * 32 + pc;
#pragma unroll
        for (int mf = 0; mf < 4; mf++)
            afB[mf] = *(const bf16x8*)(At + (mf * 16) * 32);
    }
    asm volatile("s_waitcnt lgkmcnt(4)" ::: "memory");   // afA(t)+bgC(t) ready
    __builtin_amdgcn_sched_barrier(0);
    __builtin_amdgcn_s_setprio(1);
#pragma unroll
    for (int nj = 0; nj < 4; nj++)
#pragma unroll
        for (int mf = 0; mf < 4; mf++)
            acc[mf][nj] = __builtin_amdgcn_mfma_f32_16x16x32_bf16(afA[mf], bgC[nj], acc[mf][nj], 0, 0, 0);
    __builtin_amdgcn_s_setprio(0);
    if (RSUM && rs_active) {
#pragma unroll
        for (int mf = 0; mf < 4; mf++)
#pragma unroll
            for (int e = 0; e < 8; e++) rsum[mf] += (float)afA[mf][e];
    }

    // ---------------- PH2: tile-boundary sync; stage t+3; read t+1; MFMA mg1(t)
    if (t < NT - 1) {
        asm volatile("s_waitcnt lgkmcnt(0)" ::: "memory");  // afB(t) read done (pre-barrier: buf-reuse safety)
        if (t + 2 < NT) {
            asm volatile("s_waitcnt vmcnt(4)" ::: "memory"); // tile t+1 resident (t+2 still in flight)
        } else {
            asm volatile("s_waitcnt vmcnt(0)" ::: "memory");
        }
        __builtin_amdgcn_s_barrier();                        // buf t+1 visible; buf (t+3)&3 reusable
        if (t + 3 < NT) {
            const int b3 = ((t + 3) & 3) * 8192;
            async_copy16(AsD + b3,        Ab + (t + 3) * 32);
            async_copy16(AsD + b3 + 4096, Ab + (t + 3) * 32 + (size_t)128 * lda);
            async_copy16(BsD + b3,        Bb + (t + 3) * 32);
            async_copy16(BsD + b3 + 4096, Bb + (t + 3) * 32 + (size_t)128 * ldb);
        }
        {
            const int b1 = ((t + 1) & 3) * 8192;
            const bf16* At = As + b1 + (wr * 128 + fr) * 32 + pc;
            const bf16* Bt = Bs + b1 + (wc * 64 + fr) * 32 + pc;
#pragma unroll
            for (int mf = 0; mf < 4; mf++)
                afA[mf] = *(const bf16x8*)(At + (mf * 16) * 32);
#pragma unroll
            for (int nj = 0; nj < 4; nj++)
                bgN[nj] = *(const bf16x8*)(Bt + (nj * 16) * 32);
        }
        __builtin_amdgcn_sched_barrier(0);   // pin reads before the MFMA cluster
    } else {
        asm volatile("s_waitcnt lgkmcnt(0)" ::: "memory");
        __builtin_amdgcn_sched_barrier(0);
    }
    __builtin_amdgcn_s_setprio(1);
#pragma unroll
    for (int nj = 0; nj < 4; nj++)
#pragma unroll
        for (int mf = 0; mf < 4; mf++)
            acc[4 + mf][nj] = __builtin_amdgcn_mfma_f32_16x16x32_bf16(afB[mf], bgC[nj], acc[4 + mf][nj], 0, 0, 0);
    __builtin_amdgcn_s_setprio(0);
    if (RSUM && rs_active) {
#pragma unroll
        for (int mf = 0; mf < 4; mf++)
#pragma unroll
            for (int e = 0; e < 8; e++) rsum[4 + mf] += (float)afB[mf][e];
    }
}

// K is fixed at 1024 for every call site (pv slices via koff) -> NT=32.
template<bool RSUM>
__device__ __forceinline__ void gemm_core256(const bf16* __restrict__ A,
                                             const bf16* __restrict__ B,
                                             int lda, int ldb, long koff,
                                             int m0, int n0,
                                             bf16* __restrict__ As,  // [4][8192]
                                             bf16* __restrict__ Bs,  // [4][8192]
                                             f32x4 (&acc)[8][4], float (&rsum)[8],
                                             bool rs_active)
{
    const int tid  = threadIdx.x;
    const int lane = tid & 63;
    const int wave = tid >> 6;
    const int wr = wave >> 2;                  // 0..1 m-wave
    const int wc = wave & 3;                   // 0..3 n-wave
    const int srow = tid >> 2;                 // staging row 0..127 (+128*u)
    const int spc  = tid & 3;                  // physical chunk (fixed by glds)
    const int sl   = (spc - ((srow >> 1) & 3)) & 3;  // logical chunk to fetch
    const int fr = lane & 15;
    const int q  = lane >> 4;
    const int pc = ((q + ((fr >> 1) & 3)) & 3) * 8;  // physical chunk of logical q
    const int NT = 32;                         // K=1024 / BK=32

#pragma unroll
    for (int i = 0; i < 8; i++)
#pragma unroll
        for (int j = 0; j < 4; j++) acc[i][j] = {0.f, 0.f, 0.f, 0.f};
    if (RSUM)
#pragma unroll
        for (int i = 0; i < 8; i++) rsum[i] = 0.f;

    const bf16* Ab = A + (size_t)(m0 + srow) * lda + koff + sl * 8;
    const bf16* Bb = B + (size_t)(n0 + srow) * ldb + koff + sl * 8;
    bf16* AsD = As + srow * 32 + spc * 8;
    bf16* BsD = Bs + srow * 32 + spc * 8;

    // prologue: stage tiles 0,1,2 (12 loads; oldest 4 = tile 0)
#pragma unroll
    for (int tt = 0; tt < 3; tt++) {
        async_copy16(AsD + tt * 8192,        Ab + tt * 32);
        async_copy16(AsD + tt * 8192 + 4096, Ab + tt * 32 + (size_t)128 * lda);
        async_copy16(BsD + tt * 8192,        Bb + tt * 32);
        async_copy16(BsD + tt * 8192 + 4096, Bb + tt * 32 + (size_t)128 * ldb);
    }
    asm volatile("s_waitcnt vmcnt(8)" ::: "memory");   // tile 0 staged
    __builtin_amdgcn_s_barrier();

    bf16x8 afA[4], afB[4], bg0[4], bg1[4];
    // prime afA(0), bg0(0)
    {
        const bf16* At = As + (wr * 128 + fr) * 32 + pc;
        const bf16* Bt = Bs + (wc * 64 + fr) * 32 + pc;
#pragma unroll
        for (int mf = 0; mf < 4; mf++)
            afA[mf] = *(const bf16x8*)(At + (mf * 16) * 32);
#pragma unroll
        for (int nj = 0; nj < 4; nj++)
            bg0[nj] = *(const bf16x8*)(Bt + (nj * 16) * 32);
    }

    for (int t = 0; t < NT; t += 2) {
        tile_step<RSUM>(t,     NT, Ab, Bb, lda, ldb, As, Bs, AsD, BsD,
                        wr, wc, fr, pc, afA, afB, bg0, bg1, acc, rsum, rs_active);
        tile_step<RSUM>(t + 1, NT, Ab, Bb, lda, ldb, As, Bs, AsD, BsD,
                        wr, wc, fr, pc, afA, afB, bg1, bg0, acc, rsum, rs_active);
    }
}

// Merged projections, one launch. Grid (16, 12) = 192 blocks.
// XCD swizzle (T1, hw%8 = XCD model): each XCD owns (8 x-tiles, 3 y-rows) ->
// panel footprint A 4MB + B 1.5MB vs 4MB L2 (vs full replication unswizzled).
//  byy<8 : [Q|K] = xb @ wqk^T  (m = bx*256, n = byy*256)        -> QK (ldc 2048)
//  byy>=8: V^T   = wvb @ xb^T  (id = bx+(byy-8)*16: m=(id&3)*256, n=(id>>2)*256)
__global__ __launch_bounds__(512, 1) void gemm_proj(const bf16* __restrict__ xb,
                                                    const bf16* __restrict__ wqk,
                                                    const bf16* __restrict__ wvb,
                                                    bf16* __restrict__ QK,
                                                    bf16* __restrict__ VT)
{
    __shared__ __align__(16) bf16 As[4][8192];
    __shared__ __align__(16) bf16 Bs[4][8192];

    const int hw  = blockIdx.x + 16 * blockIdx.y;      // 0..191, dispatch order
    const int xcd = hw & 7;
    const int s   = hw >> 3;                           // 0..23
    const int bx  = ((xcd & 1) << 3) | (s & 7);        // 0..15
    const int byy = (xcd >> 1) * 3 + (s >> 3);         // 0..11 (s>>3 in 0..2)

    const bf16 *A, *B;
    bf16* C;
    int ldc, m0, n0;
    if (byy < 8) {
        A = xb; B = wqk; C = QK; ldc = 2048;
        m0 = bx * 256; n0 = byy * 256;
    } else {
        const int id = bx + (byy - 8) * 16;
        A = wvb; B = xb; C = VT; ldc = 4096;
        m0 = (id & 3) * 256; n0 = (id >> 2) * 256;
    }

    f32x4 acc[8][4];
    float rs[8];
    gemm_core256<false>(A, B, 1024, 1024, 0, m0, n0, &As[0][0], &Bs[0][0], acc, rs, false);

    const int lane = threadIdx.x & 63;
    const int wave = threadIdx.x >> 6;
    const int cm = m0 + (wave >> 2) * 128 + ((lane >> 4) << 2);
    const int cn = n0 + (wave & 3) * 64 + (lane & 15);
#pragma unroll
    for (int i = 0; i < 8; i++)
#pragma unroll
        for (int j = 0; j < 4; j++)
#pragma unroll
            for (int r = 0; r < 4; r++)
                C[(size_t)(cm + i * 16 + r) * ldc + (cn + j * 16)] = (bf16)acc[i][j][r];
}

// E = exp((Q @ K^T)/32), bf16. Grid (16, 16); shift-free softmax numerator
// (scores ~N(0,1): exp safe in fp32/bf16; softmax is shift-invariant).
// XCD swizzle: each XCD owns (8 m-tiles, 4 n-tiles): A 4MB + B 2MB footprint.
__global__ __launch_bounds__(512, 1) void gemm_exp(const bf16* __restrict__ QK,
                                                   bf16* __restrict__ E)
{
    __shared__ __align__(16) bf16 As[4][8192];
    __shared__ __align__(16) bf16 Bs[4][8192];

    const int hw  = blockIdx.x + 16 * blockIdx.y;      // 0..255
    const int xcd = hw & 7;
    const int s   = hw >> 3;                           // 0..31
    const int bx  = ((xcd & 1) << 3) | (s & 7);        // 0..15
    const int by  = ((xcd >> 1) << 2) | (s >> 3);      // 0..15

    const int m0 = bx * 256;
    const int n0 = by * 256;
    f32x4 acc[8][4];
    float rs[8];
    gemm_core256<false>(QK, QK + 1024, 2048, 2048, 0, m0, n0, &As[0][0], &Bs[0][0], acc, rs, false);

    const int lane = threadIdx.x & 63;
    const int wave = threadIdx.x >> 6;
    const int cm = m0 + (wave >> 2) * 128 + ((lane >> 4) << 2);
    const int cn = n0 + (wave & 3) * 64 + (lane & 15);
#pragma unroll
    for (int i = 0; i < 8; i++)
#pragma unroll
        for (int j = 0; j < 4; j++)
#pragma unroll
            for (int r = 0; r < 4; r++)
                E[(size_t)(cm + i * 16 + r) * 4096 + (cn + j * 16)] =
                    (bf16)__expf(acc[i][j][r] * 0.03125f);
}

// PV partials + rowsum-from-A-frags. Grid (16 m, 4 n, 4 z); K=1024/slice.
// XCD swizzle: each XCD owns (8 m-tiles, all 4 n-tiles, ONE z): A 4MB + B 2MB.
// z=0 stores to out, z>=1 to p1+(z-1)*16M. Blocks with n-tile==0, waves with
// wc==0 accumulate rowsum partials from the E fragments they already load.
__global__ __launch_bounds__(512, 1) void gemm_pv(const bf16* __restrict__ E,
                                                  const bf16* __restrict__ VT,
                                                  float* __restrict__ out,
                                                  float* __restrict__ p1,
                                                  float* __restrict__ rowsum)
{
    __shared__ __align__(16) bf16 As[4][8192];
    __shared__ __align__(16) bf16 Bs[4][8192];

    const int hw  = blockIdx.x + 16 * blockIdx.y + 64 * blockIdx.z;  // 0..255
    const int xcd = hw & 7;
    const int s   = hw >> 3;                           // 0..31
    const int bx  = ((xcd & 1) << 3) | (s & 7);        // 0..15
    const int by  = s >> 3;                            // 0..3
    const int bz  = xcd >> 1;                          // 0..3

    const int m0 = bx * 256;
    const int n0 = by * 256;
    const long koff = (long)bz * 1024;
    const bool rs_active = (by == 0) && (((threadIdx.x >> 6) & 3) == 0);

    f32x4 acc[8][4];
    float rs[8];
    gemm_core256<true>(E, VT, 4096, 4096, koff, m0, n0, &As[0][0], &Bs[0][0], acc, rs, rs_active);

    const int lane = threadIdx.x & 63;
    const int wave = threadIdx.x >> 6;
    if (rs_active) {
#pragma unroll
        for (int i = 0; i < 8; i++) {
            rs[i] += __shfl_xor(rs[i], 16);
            rs[i] += __shfl_xor(rs[i], 32);
        }
        if (lane < 16) {
            const int rbase = m0 + (wave >> 2) * 128;
#pragma unroll
            for (int i = 0; i < 8; i++)
                unsafeAtomicAdd(&rowsum[rbase + i * 16 + lane], rs[i]);
        }
    }

    float* C = (bz == 0) ? out : p1 + (size_t)(bz - 1) * SEQ * 1024;
    const int cm = m0 + (wave >> 2) * 128 + ((lane >> 4) << 2);
    const int cn = n0 + (wave & 3) * 64 + (lane & 15);
#pragma unroll
    for (int i = 0; i < 8; i++)
#pragma unroll
        for (int j = 0; j < 4; j++)
#pragma unroll
            for (int r = 0; r < 4; r++)
                C[(size_t)(cm + i * 16 + r) * 1024 + (cn + j * 16)] = acc[i][j][r];
}

// one block per row m: out[m] = (out[m] + p1[m] + p2[m] + p3[m]) / rowsum[m]
__global__ __launch_bounds__(256) void reduce_norm(float* __restrict__ out,
                                                   const float* __restrict__ p1,
                                                   const float* __restrict__ p2,
                                                   const float* __restrict__ p3,
                                                   const float* __restrict__ rowsum)
{
    const int m = blockIdx.x;
    const float inv = 1.f / rowsum[m];
    const size_t off = (size_t)m * 1024 + threadIdx.x * 4;
    float4 a = *(const float4*)(out + off);
    float4 b = *(const float4*)(p1 + off);
    float4 c = *(const float4*)(p2 + off);
    float4 d = *(const float4*)(p3 + off);
    float4 o;
    o.x = (a.x + b.x + c.x + d.x) * inv;
    o.y = (a.y + b.y + c.y + d.y) * inv;
    o.z = (a.z + b.z + c.z + d.z) * inv;
    o.w = (a.w + b.w + c.w + d.w) * inv;
    *(float4*)(out + off) = o;
}

extern "C" void kernel_launch(void* const* d_in, const int* in_sizes, int n_in,
                              void* d_out, int out_size, void* d_ws, size_t ws_size,
                              hipStream_t stream)
{
    const float* x  = (const float*)d_in[0];   // (4096, 1024) fp32
    const float* wq = (const float*)d_in[1];   // (1024, 1024) fp32
    const float* wk = (const float*)d_in[2];
    const float* wv = (const float*)d_in[3];
    float* out = (float*)d_out;                // (4096, 1024) fp32

    char* ws = (char*)d_ws;
    const size_t MB = 1024 * 1024;
    bf16*  E   = (bf16*)(ws);                   // [0,32)   4096x4096 bf16
    float* p1  = (float*)(ws + 32 * MB);        // [32,48)  PV partial z=1
    float* p2  = (float*)(ws + 48 * MB);        // [48,64)  PV partial z=2
    float* p3  = (float*)(ws + 64 * MB);        // [64,80)  PV partial z=3
    bf16*  xb  = (bf16*)(ws + 32 * MB);         // [32,40)  (dead before p1 written)
    bf16*  wqk = (bf16*)(ws + 40 * MB);         // [40,44)  W_Q|W_K (2048x1024)
    bf16*  wvb = (bf16*)(ws + 44 * MB);         // [44,46)
    bf16*  QK  = (bf16*)(ws + 64 * MB);         // [64,80)  4096x2048 (dead before p3)
    bf16*  VT  = (bf16*)(ws + 80 * MB);         // [80,88)  1024x4096 = V^T
    float* rsm = (float*)(ws + 88 * MB);        // [88,88+16KB) rowsum

    // 0. convert inputs to bf16 + zero rowsum
    prep_all<<<dim3(7172), dim3(256), 0, stream>>>(x, wq, wk, wv, xb, wqk, wvb, rsm);
    // 1. merged projections: QK (128 blocks) + VT (64 blocks)
    gemm_proj<<<dim3(16, 12), dim3(512), 0, stream>>>(xb, wqk, wvb, QK, VT);
    // 2. E = exp((Q @ K^T)/32)  (256 blocks = 1/CU)
    gemm_exp<<<dim3(16, 16), dim3(512), 0, stream>>>(QK, E);
    // 3. PV partials (split-K 4) + rowsum  (256 blocks = 1/CU)
    gemm_pv<<<dim3(16, 4, 4), dim3(512), 0, stream>>>(E, VT, out, p1, rsm);
    // 4. out[m] = (out + p1 + p2 + p3)[m] / rowsum[m]
    reduce_norm<<<dim3(4096), dim3(256), 0, stream>>>(out, p1, p2, p3, rsm);
}

// Round 7
// 198.653 us; speedup vs baseline: 1.1733x; 1.1733x over previous
//
#include <hip/hip_runtime.h>

typedef __bf16 bf16;
typedef __bf16 bf16x4 __attribute__((ext_vector_type(4)));
typedef __bf16 bf16x8 __attribute__((ext_vector_type(8)));
typedef float f32x4 __attribute__((ext_vector_type(4)));

#define SEQ 4096
#define EMB 1024

// async global->LDS, 16B per lane; LDS dest = wave-uniform base + lane*16 (m97/m104)
__device__ __forceinline__ void async_copy16(void* lds, const void* g) {
    __builtin_amdgcn_global_load_lds(
        (const __attribute__((address_space(1))) unsigned int*)g,
        (__attribute__((address_space(3))) unsigned int*)lds,
        16, 0, 0);
}

// One prep kernel: fp32->bf16 of x, W_Q|W_K (stacked), W_V; zero rowsum.
__global__ __launch_bounds__(256) void prep_all(const float* __restrict__ x,
                                                const float* __restrict__ wq,
                                                const float* __restrict__ wk,
                                                const float* __restrict__ wv,
                                                bf16* __restrict__ xb,
                                                bf16* __restrict__ wqk,
                                                bf16* __restrict__ wvb,
                                                float* __restrict__ rowsum)
{
    const int u = blockIdx.x * 256 + threadIdx.x;
    const float* src;
    bf16* dst;
    int off;
    if (u < 1048576)      { src = x;  dst = xb;               off = u; }
    else if (u < 1310720) { src = wq; dst = wqk;              off = u - 1048576; }
    else if (u < 1572864) { src = wk; dst = wqk + EMB * EMB;  off = u - 1310720; }
    else if (u < 1835008) { src = wv; dst = wvb;              off = u - 1572864; }
    else {                // u < 1836032: zero rowsum[4096]
        *(float4*)(rowsum + (size_t)(u - 1835008) * 4) = float4{0.f, 0.f, 0.f, 0.f};
        return;
    }
    float4 f = *(const float4*)(src + (size_t)off * 4);
    bf16x4 v = { (bf16)f.x, (bf16)f.y, (bf16)f.z, (bf16)f.w };
    *(bf16x4*)(dst + (size_t)off * 4) = v;
}

// ---------------------------------------------------------------------------
// 256x256 tile GEMM core, BK=32, 512 threads = 8 waves (2 m-waves x 4 n-waves),
// per-wave output 128x64. R7 = R5 wait structure + 3-deep staging + XCD swz.
//  - 4 LDS buffers (t&3). Staging runs THREE tiles ahead, split across phases
//    (A(t+3) in PH1, B(t+3) in PH2 post-barrier); counted vmcnt(6/4/0) per
//    tile -> 2+ tiles of slack for L2/HBM latency. NO lgkm drain pre-barrier:
//    lgkm(8) in PH2(t-1) already proves all reads of buf(t-1) complete before
//    each wave reaches the PH2(t-1) barrier; buf(t-1) is only overwritten
//    after all waves pass it (R6's lgkm(0)-pre-barrier serialized LDS latency
//    into the sync and cost 12%).
//  - 2 phases/tile, ds_reads one phase ahead of their MFMA cluster:
//    PH1(t): stage A(t+3); issue afB(t); lgkm(4); MFMA mg0 (afA x bgC).
//    PH2(t): vmcnt(6|4|0); barrier; stage B(t+3); issue afA(t+1)+bgN(t+1);
//            lgkm(8) [= afB(t) done]; MFMA mg1 (afB x bgC).
// LDS row stride 32 elems (64B); k-chunk rotation g(r)=(r>>1)&3 on BOTH sides
// (per-lane global-source permutation at staging + read offset): 2-way = free
// (R5 verified: SQ_LDS_BANK_CONFLICT = 0).
// RSUM: per-row sums of A-frags (lane fr = row; q-lanes = disjoint k-chunks).
// ---------------------------------------------------------------------------
template<bool RSUM>
__device__ __forceinline__ void tile_step(int t, int NT,
                                          const bf16* __restrict__ Ab,
                                          const bf16* __restrict__ Bb,
                                          int lda, int ldb,
                                          bf16* __restrict__ As,
                                          bf16* __restrict__ Bs,
                                          bf16* __restrict__ AsD,
                                          bf16* __restrict__ BsD,
                                          int wr, int wc, int fr, int pc,
                                          bf16x8 (&afA)[4], bf16x8 (&afB)[4],
                                          bf16x8 (&bgC)[4], bf16x8 (&bgN)[4],
                                          f32x4 (&acc)[8][4], float (&rsum)[8],
                                          bool rs_active)
{
    // ---------------- PH1: stage A(t+3); issue afB(t); MFMA mg0 = afA x bgC
    if (t + 3 < NT) {
        const int b3 = ((t + 3) & 3) * 8192;
        async_copy16(AsD + b3,        Ab + (t + 3) * 32);
        async_copy16(AsD + b3 + 4096, Ab + (t + 3) * 32 + (size_t)128 * lda);
    }
    {
        const bf16* At = As + (t & 3) * 8192 + (wr * 128 + 64 + fr) * 32 + pc;
#pragma unroll
        for (int mf = 0; mf < 4; mf++)
            afB[mf] = *(const bf16x8*)(At + (mf * 16) * 32);
    }
    asm volatile("s_waitcnt lgkmcnt(4)" ::: "memory");   // afA(t)+bgC(t) ready
    __builtin_amdgcn_sched_barrier(0);
    __builtin_amdgcn_s_setprio(1);
#pragma unroll
    for (int nj = 0; nj < 4; nj++)
#pragma unroll
        for (int mf = 0; mf < 4; mf++)
            acc[mf][nj] = __builtin_amdgcn_mfma_f32_16x16x32_bf16(afA[mf], bgC[nj], acc[mf][nj], 0, 0, 0);
    __builtin_amdgcn_s_setprio(0);
    if (RSUM && rs_active) {
#pragma unroll
        for (int mf = 0; mf < 4; mf++)
#pragma unroll
            for (int e = 0; e < 8; e++) rsum[mf] += (float)afA[mf][e];
    }

    // ---------------- PH2: tile sync; stage B(t+3); read t+1; MFMA mg1(t)
    if (t < NT - 1) {
        if (t + 3 < NT) {
            asm volatile("s_waitcnt vmcnt(6)" ::: "memory"); // tile t+1 resident
        } else if (t + 2 < NT) {
            asm volatile("s_waitcnt vmcnt(4)" ::: "memory");
        } else {
            asm volatile("s_waitcnt vmcnt(0)" ::: "memory");
        }
        __builtin_amdgcn_s_barrier();            // buf t+1 visible; buf (t+3)&3 reusable
        if (t + 3 < NT) {
            const int b3 = ((t + 3) & 3) * 8192;
            async_copy16(BsD + b3,        Bb + (t + 3) * 32);
            async_copy16(BsD + b3 + 4096, Bb + (t + 3) * 32 + (size_t)128 * ldb);
        }
        {
            const int b1 = ((t + 1) & 3) * 8192;
            const bf16* At = As + b1 + (wr * 128 + fr) * 32 + pc;
            const bf16* Bt = Bs + b1 + (wc * 64 + fr) * 32 + pc;
#pragma unroll
            for (int mf = 0; mf < 4; mf++)
                afA[mf] = *(const bf16x8*)(At + (mf * 16) * 32);
#pragma unroll
            for (int nj = 0; nj < 4; nj++)
                bgN[nj] = *(const bf16x8*)(Bt + (nj * 16) * 32);
        }
        asm volatile("s_waitcnt lgkmcnt(8)" ::: "memory");   // afB(t) done
        __builtin_amdgcn_sched_barrier(0);
    } else {
        asm volatile("s_waitcnt lgkmcnt(0)" ::: "memory");
        __builtin_amdgcn_sched_barrier(0);
    }
    __builtin_amdgcn_s_setprio(1);
#pragma unroll
    for (int nj = 0; nj < 4; nj++)
#pragma unroll
        for (int mf = 0; mf < 4; mf++)
            acc[4 + mf][nj] = __builtin_amdgcn_mfma_f32_16x16x32_bf16(afB[mf], bgC[nj], acc[4 + mf][nj], 0, 0, 0);
    __builtin_amdgcn_s_setprio(0);
    if (RSUM && rs_active) {
#pragma unroll
        for (int mf = 0; mf < 4; mf++)
#pragma unroll
            for (int e = 0; e < 8; e++) rsum[4 + mf] += (float)afB[mf][e];
    }
}

// K is fixed at 1024 for every call site (pv slices via koff) -> NT=32.
template<bool RSUM>
__device__ __forceinline__ void gemm_core256(const bf16* __restrict__ A,
                                             const bf16* __restrict__ B,
                                             int lda, int ldb, long koff,
                                             int m0, int n0,
                                             bf16* __restrict__ As,  // [4][8192]
                                             bf16* __restrict__ Bs,  // [4][8192]
                                             f32x4 (&acc)[8][4], float (&rsum)[8],
                                             bool rs_active)
{
    const int tid  = threadIdx.x;
    const int lane = tid & 63;
    const int wave = tid >> 6;
    const int wr = wave >> 2;                  // 0..1 m-wave
    const int wc = wave & 3;                   // 0..3 n-wave
    const int srow = tid >> 2;                 // staging row 0..127 (+128*u)
    const int spc  = tid & 3;                  // physical chunk (fixed by glds)
    const int sl   = (spc - ((srow >> 1) & 3)) & 3;  // logical chunk to fetch
    const int fr = lane & 15;
    const int q  = lane >> 4;
    const int pc = ((q + ((fr >> 1) & 3)) & 3) * 8;  // physical chunk of logical q
    const int NT = 32;                         // K=1024 / BK=32

#pragma unroll
    for (int i = 0; i < 8; i++)
#pragma unroll
        for (int j = 0; j < 4; j++) acc[i][j] = {0.f, 0.f, 0.f, 0.f};
    if (RSUM)
#pragma unroll
        for (int i = 0; i < 8; i++) rsum[i] = 0.f;

    const bf16* Ab = A + (size_t)(m0 + srow) * lda + koff + sl * 8;
    const bf16* Bb = B + (size_t)(n0 + srow) * ldb + koff + sl * 8;
    bf16* AsD = As + srow * 32 + spc * 8;
    bf16* BsD = Bs + srow * 32 + spc * 8;

    // prologue: stage tiles 0,1,2 in A0,B0,A1,B1,A2,B2 order (12 loads) so the
    // steady-state vmcnt counts (6/4/0) hold from t=0.
#pragma unroll
    for (int tt = 0; tt < 3; tt++) {
        async_copy16(AsD + tt * 8192,        Ab + tt * 32);
        async_copy16(AsD + tt * 8192 + 4096, Ab + tt * 32 + (size_t)128 * lda);
        async_copy16(BsD + tt * 8192,        Bb + tt * 32);
        async_copy16(BsD + tt * 8192 + 4096, Bb + tt * 32 + (size_t)128 * ldb);
    }
    asm volatile("s_waitcnt vmcnt(8)" ::: "memory");   // tile 0 staged
    __builtin_amdgcn_s_barrier();

    bf16x8 afA[4], afB[4], bg0[4], bg1[4];
    // prime afA(0), bg0(0): 8 ds_reads left outstanding (steady-state invariant)
    {
        const bf16* At = As + (wr * 128 + fr) * 32 + pc;
        const bf16* Bt = Bs + (wc * 64 + fr) * 32 + pc;
#pragma unroll
        for (int mf = 0; mf < 4; mf++)
            afA[mf] = *(const bf16x8*)(At + (mf * 16) * 32);
#pragma unroll
        for (int nj = 0; nj < 4; nj++)
            bg0[nj] = *(const bf16x8*)(Bt + (nj * 16) * 32);
    }

    for (int t = 0; t < NT; t += 2) {
        tile_step<RSUM>(t,     NT, Ab, Bb, lda, ldb, As, Bs, AsD, BsD,
                        wr, wc, fr, pc, afA, afB, bg0, bg1, acc, rsum, rs_active);
        tile_step<RSUM>(t + 1, NT, Ab, Bb, lda, ldb, As, Bs, AsD, BsD,
                        wr, wc, fr, pc, afA, afB, bg1, bg0, acc, rsum, rs_active);
    }
}

// Merged projections, one launch. Grid (16, 12) = 192 blocks.
// XCD swizzle (T1, hw%8 = XCD model; R6: FETCH halved -> keep): each XCD owns
// (8 x-tiles, 3 y-rows).
__global__ __launch_bounds__(512, 1) void gemm_proj(const bf16* __restrict__ xb,
                                                    const bf16* __restrict__ wqk,
                                                    const bf16* __restrict__ wvb,
                                                    bf16* __restrict__ QK,
                                                    bf16* __restrict__ VT)
{
    __shared__ __align__(16) bf16 As[4][8192];
    __shared__ __align__(16) bf16 Bs[4][8192];

    const int hw  = blockIdx.x + 16 * blockIdx.y;      // 0..191, dispatch order
    const int xcd = hw & 7;
    const int s   = hw >> 3;                           // 0..23
    const int bx  = ((xcd & 1) << 3) | (s & 7);        // 0..15
    const int byy = (xcd >> 1) * 3 + (s >> 3);         // 0..11

    const bf16 *A, *B;
    bf16* C;
    int ldc, m0, n0;
    if (byy < 8) {
        A = xb; B = wqk; C = QK; ldc = 2048;
        m0 = bx * 256; n0 = byy * 256;
    } else {
        const int id = bx + (byy - 8) * 16;
        A = wvb; B = xb; C = VT; ldc = 4096;
        m0 = (id & 3) * 256; n0 = (id >> 2) * 256;
    }

    f32x4 acc[8][4];
    float rs[8];
    gemm_core256<false>(A, B, 1024, 1024, 0, m0, n0, &As[0][0], &Bs[0][0], acc, rs, false);

    const int lane = threadIdx.x & 63;
    const int wave = threadIdx.x >> 6;
    const int cm = m0 + (wave >> 2) * 128 + ((lane >> 4) << 2);
    const int cn = n0 + (wave & 3) * 64 + (lane & 15);
#pragma unroll
    for (int i = 0; i < 8; i++)
#pragma unroll
        for (int j = 0; j < 4; j++)
#pragma unroll
            for (int r = 0; r < 4; r++)
                C[(size_t)(cm + i * 16 + r) * ldc + (cn + j * 16)] = (bf16)acc[i][j][r];
}

// E = exp((Q @ K^T)/32), bf16. Grid (16, 16). XCD swizzle: (8 m, 4 n)/XCD.
__global__ __launch_bounds__(512, 1) void gemm_exp(const bf16* __restrict__ QK,
                                                   bf16* __restrict__ E)
{
    __shared__ __align__(16) bf16 As[4][8192];
    __shared__ __align__(16) bf16 Bs[4][8192];

    const int hw  = blockIdx.x + 16 * blockIdx.y;      // 0..255
    const int xcd = hw & 7;
    const int s   = hw >> 3;                           // 0..31
    const int bx  = ((xcd & 1) << 3) | (s & 7);        // 0..15
    const int by  = ((xcd >> 1) << 2) | (s >> 3);      // 0..15

    const int m0 = bx * 256;
    const int n0 = by * 256;
    f32x4 acc[8][4];
    float rs[8];
    gemm_core256<false>(QK, QK + 1024, 2048, 2048, 0, m0, n0, &As[0][0], &Bs[0][0], acc, rs, false);

    const int lane = threadIdx.x & 63;
    const int wave = threadIdx.x >> 6;
    const int cm = m0 + (wave >> 2) * 128 + ((lane >> 4) << 2);
    const int cn = n0 + (wave & 3) * 64 + (lane & 15);
#pragma unroll
    for (int i = 0; i < 8; i++)
#pragma unroll
        for (int j = 0; j < 4; j++)
#pragma unroll
            for (int r = 0; r < 4; r++)
                E[(size_t)(cm + i * 16 + r) * 4096 + (cn + j * 16)] =
                    (bf16)__expf(acc[i][j][r] * 0.03125f);
}

// PV partials + rowsum-from-A-frags. Grid (16 m, 4 n, 4 z); K=1024/slice.
// XCD swizzle: each XCD owns (8 m, all 4 n, ONE z). z=0 -> out, z>=1 -> p1+..
__global__ __launch_bounds__(512, 1) void gemm_pv(const bf16* __restrict__ E,
                                                  const bf16* __restrict__ VT,
                                                  float* __restrict__ out,
                                                  float* __restrict__ p1,
                                                  float* __restrict__ rowsum)
{
    __shared__ __align__(16) bf16 As[4][8192];
    __shared__ __align__(16) bf16 Bs[4][8192];

    const int hw  = blockIdx.x + 16 * blockIdx.y + 64 * blockIdx.z;  // 0..255
    const int xcd = hw & 7;
    const int s   = hw >> 3;                           // 0..31
    const int bx  = ((xcd & 1) << 3) | (s & 7);        // 0..15
    const int by  = s >> 3;                            // 0..3
    const int bz  = xcd >> 1;                          // 0..3

    const int m0 = bx * 256;
    const int n0 = by * 256;
    const long koff = (long)bz * 1024;
    const bool rs_active = (by == 0) && (((threadIdx.x >> 6) & 3) == 0);

    f32x4 acc[8][4];
    float rs[8];
    gemm_core256<true>(E, VT, 4096, 4096, koff, m0, n0, &As[0][0], &Bs[0][0], acc, rs, rs_active);

    const int lane = threadIdx.x & 63;
    const int wave = threadIdx.x >> 6;
    if (rs_active) {
#pragma unroll
        for (int i = 0; i < 8; i++) {
            rs[i] += __shfl_xor(rs[i], 16);
            rs[i] += __shfl_xor(rs[i], 32);
        }
        if (lane < 16) {
            const int rbase = m0 + (wave >> 2) * 128;
#pragma unroll
            for (int i = 0; i < 8; i++)
                unsafeAtomicAdd(&rowsum[rbase + i * 16 + lane], rs[i]);
        }
    }

    float* C = (bz == 0) ? out : p1 + (size_t)(bz - 1) * SEQ * 1024;
    const int cm = m0 + (wave >> 2) * 128 + ((lane >> 4) << 2);
    const int cn = n0 + (wave & 3) * 64 + (lane & 15);
#pragma unroll
    for (int i = 0; i < 8; i++)
#pragma unroll
        for (int j = 0; j < 4; j++)
#pragma unroll
            for (int r = 0; r < 4; r++)
                C[(size_t)(cm + i * 16 + r) * 1024 + (cn + j * 16)] = acc[i][j][r];
}

// one block per row m: out[m] = (out[m] + p1[m] + p2[m] + p3[m]) / rowsum[m]
__global__ __launch_bounds__(256) void reduce_norm(float* __restrict__ out,
                                                   const float* __restrict__ p1,
                                                   const float* __restrict__ p2,
                                                   const float* __restrict__ p3,
                                                   const float* __restrict__ rowsum)
{
    const int m = blockIdx.x;
    const float inv = 1.f / rowsum[m];
    const size_t off = (size_t)m * 1024 + threadIdx.x * 4;
    float4 a = *(const float4*)(out + off);
    float4 b = *(const float4*)(p1 + off);
    float4 c = *(const float4*)(p2 + off);
    float4 d = *(const float4*)(p3 + off);
    float4 o;
    o.x = (a.x + b.x + c.x + d.x) * inv;
    o.y = (a.y + b.y + c.y + d.y) * inv;
    o.z = (a.z + b.z + c.z + d.z) * inv;
    o.w = (a.w + b.w + c.w + d.w) * inv;
    *(float4*)(out + off) = o;
}

extern "C" void kernel_launch(void* const* d_in, const int* in_sizes, int n_in,
                              void* d_out, int out_size, void* d_ws, size_t ws_size,
                              hipStream_t stream)
{
    const float* x  = (const float*)d_in[0];   // (4096, 1024) fp32
    const float* wq = (const float*)d_in[1];   // (1024, 1024) fp32
    const float* wk = (const float*)d_in[2];
    const float* wv = (const float*)d_in[3];
    float* out = (float*)d_out;                // (4096, 1024) fp32

    char* ws = (char*)d_ws;
    const size_t MB = 1024 * 1024;
    bf16*  E   = (bf16*)(ws);                   // [0,32)   4096x4096 bf16
    float* p1  = (float*)(ws + 32 * MB);        // [32,48)  PV partial z=1
    float* p2  = (float*)(ws + 48 * MB);        // [48,64)  PV partial z=2
    float* p3  = (float*)(ws + 64 * MB);        // [64,80)  PV partial z=3
    bf16*  xb  = (bf16*)(ws + 32 * MB);         // [32,40)  (dead before p1 written)
    bf16*  wqk = (bf16*)(ws + 40 * MB);         // [40,44)  W_Q|W_K (2048x1024)
    bf16*  wvb = (bf16*)(ws + 44 * MB);         // [44,46)
    bf16*  QK  = (bf16*)(ws + 64 * MB);         // [64,80)  4096x2048 (dead before p3)
    bf16*  VT  = (bf16*)(ws + 80 * MB);         // [80,88)  1024x4096 = V^T
    float* rsm = (float*)(ws + 88 * MB);        // [88,88+16KB) rowsum

    // 0. convert inputs to bf16 + zero rowsum
    prep_all<<<dim3(7172), dim3(256), 0, stream>>>(x, wq, wk, wv, xb, wqk, wvb, rsm);
    // 1. merged projections: QK (128 blocks) + VT (64 blocks)
    gemm_proj<<<dim3(16, 12), dim3(512), 0, stream>>>(xb, wqk, wvb, QK, VT);
    // 2. E = exp((Q @ K^T)/32)  (256 blocks = 1/CU)
    gemm_exp<<<dim3(16, 16), dim3(512), 0, stream>>>(QK, E);
    // 3. PV partials (split-K 4) + rowsum  (256 blocks = 1/CU)
    gemm_pv<<<dim3(16, 4, 4), dim3(512), 0, stream>>>(E, VT, out, p1, rsm);
    // 4. out[m] = (out + p1 + p2 + p3)[m] / rowsum[m]
    reduce_norm<<<dim3(4096), dim3(256), 0, stream>>>(out, p1, p2, p3, rsm);
}